// Round 2
// baseline (323.445 us; speedup 1.0000x reference)
//
#include <hip/hip_runtime.h>

#define K_CODES 4096
#define DIM 256
#define SEQ 2048
#define NTOK 65536

typedef __bf16 bf16x8 __attribute__((ext_vector_type(8)));
typedef float floatx4 __attribute__((ext_vector_type(4)));
typedef unsigned short u16x8 __attribute__((ext_vector_type(8)));

__device__ __forceinline__ unsigned short f2bf(float f) {
    union { float f; unsigned int u; } v; v.f = f;
    unsigned int u = v.u;
    unsigned int r = u + 0x7fffu + ((u >> 16) & 1u);   // RNE
    return (unsigned short)(r >> 16);
}

// async global->LDS, 16B per lane. LDS dest = wave-uniform base + lane*16.
__device__ __forceinline__ void async_cp16(const void* g, const void* lds_base) {
    typedef __attribute__((address_space(1))) const unsigned int guint;
    typedef __attribute__((address_space(3))) unsigned int luint;
    __builtin_amdgcn_global_load_lds(
        (guint*)(unsigned long long)g,
        (luint*)(unsigned int)(unsigned long long)lds_base,
        16, 0, 0);
}

// ---------------- kernel 1: swizzled bf16 codebook + norms + zero loss ------
// Grid: 128 blocks (one per 32-code chunk), 256 threads.
// Swizzle layout: cb_swz[(((c*16 + ns*8 + ks)*64) + quad*16 + col)*8 + j]
//   = bf16(codebook[c*32 + ns*16 + col][quad*8 + ks*32 + j])
// -> each 1KB fragment block is exactly one wave's ds_read_b128, lane-contiguous.
__global__ __launch_bounds__(256) void k_prep(const float* __restrict__ cb,
        unsigned short* __restrict__ cb_swz, float* __restrict__ norms,
        float* __restrict__ loss_slot) {
    const int c = blockIdx.x;
    const int t = threadIdx.x;
    const int row_loc = t >> 3;       // 0..31 code within chunk
    const int ks = t & 7;             // k-slice
    const int row = c * 32 + row_loc;
    const float* src = cb + (size_t)row * DIM + ks * 32;
    float vals[32];
    float s = 0.0f;
    #pragma unroll
    for (int i = 0; i < 8; ++i) {
        floatx4 v = *(const floatx4*)(src + i * 4);
        #pragma unroll
        for (int j = 0; j < 4; ++j) { vals[i * 4 + j] = v[j]; s += v[j] * v[j]; }
    }
    const int ns = row_loc >> 4, col = row_loc & 15;
    #pragma unroll
    for (int quad = 0; quad < 4; ++quad) {
        u16x8 p;
        #pragma unroll
        for (int j = 0; j < 8; ++j) p[j] = f2bf(vals[quad * 8 + j]);
        *(u16x8*)(cb_swz + ((size_t)((c * 16 + ns * 8 + ks) * 64 + quad * 16 + col)) * 8) = p;
    }
    // full-row norm: reduce across the 8 ks-threads (adjacent lanes)
    s += __shfl_xor(s, 1); s += __shfl_xor(s, 2); s += __shfl_xor(s, 4);
    if (ks == 0) norms[row] = s;
    if (c == 0 && t == 0) *loss_slot = 0.0f;
}

// ---------------- kernel 2: MFMA distance GEMM + argmin ---------------------
// Block: 128 threads = 2 waves; 64 tokens/wave (m=4) -> 128 tokens/block.
// Grid: 512. LDS: X-stage 2 x 8448 ushorts (one-time), reused as 2 x 16KB ring.
__global__ __launch_bounds__(128, 2) void k_argmin(const float* __restrict__ x,
        const unsigned short* __restrict__ cb_swz, const float* __restrict__ norms,
        int* __restrict__ out_idx) {
    __shared__ __align__(16) unsigned short smem[16896];   // 33792 B
    const int t = threadIdx.x;
    const int lane = t & 63, w = t >> 6;
    const int col = lane & 15, quad = lane >> 4;
    const int tok0 = blockIdx.x * 128;
    const int b = tok0 >> 11, s0 = tok0 & 2047;
    const float* xin = x + (size_t)b * DIM * SEQ;

    // ---- one-time: stage X (as -2x bf16) per-wave, load A fragments
    unsigned short* xs = &smem[w * 8448];
    bf16x8 af[4][8];
    const int dl = lane >> 3, so = (lane & 7) * 4;
    for (int sub = 0; sub < 2; ++sub) {
        const int sbase = s0 + w * 64 + sub * 32;
        for (int i = 0; i < 32; ++i) {
            int d = i * 8 + dl;
            floatx4 v = *(const floatx4*)(xin + (size_t)d * SEQ + sbase + so);
            #pragma unroll
            for (int j = 0; j < 4; ++j) xs[(so + j) * 264 + d] = f2bf(-2.0f * v[j]);
        }
        #pragma unroll
        for (int mm = 0; mm < 2; ++mm)
            #pragma unroll
            for (int ks = 0; ks < 8; ++ks)
                af[sub * 2 + mm][ks] =
                    *(const bf16x8*)&xs[(mm * 16 + col) * 264 + quad * 8 + ks * 32];
    }
    __syncthreads();   // X areas dead; ring takes over smem[0..16384) ushorts

    float minv[4][4]; int mini[4][4];
    #pragma unroll
    for (int m = 0; m < 4; ++m)
        #pragma unroll
        for (int r = 0; r < 4; ++r) { minv[m][r] = 3.0e38f; mini[m][r] = 0; }

    // stage chunk 0 -> ring buf 0 (8 rounds x 128 lanes x 16B = 16 KB)
    {
        const char* src = (const char*)cb_swz;
        char* dst = (char*)smem;
        #pragma unroll
        for (int i = 0; i < 8; ++i)
            async_cp16(src + i * 2048 + w * 1024 + lane * 16,
                       dst + i * 2048 + w * 1024);
    }

    for (int c = 0; c < 128; ++c) {
        __syncthreads();   // publish chunk c (prefetch issued a full compute-window ago)
        if (c + 1 < 128) {
            const char* src = (const char*)cb_swz + (size_t)(c + 1) * 16384;
            char* dst = (char*)smem + ((c + 1) & 1) * 16384;
            #pragma unroll
            for (int i = 0; i < 8; ++i)
                async_cp16(src + i * 2048 + w * 1024 + lane * 16,
                           dst + i * 2048 + w * 1024);
        }
        const unsigned short* buf = smem + (c & 1) * 8192;
        #pragma unroll
        for (int ns = 0; ns < 2; ++ns) {
            float nv = norms[c * 32 + ns * 16 + col];
            bf16x8 bfrag[8];
            #pragma unroll
            for (int ks = 0; ks < 8; ++ks)   // lane-contiguous 1KB -> conflict-free
                bfrag[ks] = *(const bf16x8*)&buf[((ns * 8 + ks) * 64 + lane) * 8];
            floatx4 acc[4];
            #pragma unroll
            for (int m = 0; m < 4; ++m) acc[m] = (floatx4){nv, nv, nv, nv};
            #pragma unroll
            for (int ks = 0; ks < 8; ++ks)
                #pragma unroll
                for (int m = 0; m < 4; ++m)
                    acc[m] = __builtin_amdgcn_mfma_f32_16x16x32_bf16(
                                 af[m][ks], bfrag[ks], acc[m], 0, 0, 0);
            const int code = c * 32 + ns * 16 + col;
            #pragma unroll
            for (int m = 0; m < 4; ++m)
                #pragma unroll
                for (int r = 0; r < 4; ++r)
                    if (acc[m][r] < minv[m][r]) { minv[m][r] = acc[m][r]; mini[m][r] = code; }
        }
    }

    // ---- reduce across the 16 column-lanes, write indices
    #pragma unroll
    for (int m = 0; m < 4; ++m)
        #pragma unroll
        for (int r = 0; r < 4; ++r) {
            float mv = minv[m][r]; int mi = mini[m][r];
            #pragma unroll
            for (int off = 8; off >= 1; off >>= 1) {
                float ov = __shfl_xor(mv, off);
                int   oi = __shfl_xor(mi, off);
                if (ov < mv || (ov == mv && oi < mi)) { mv = ov; mi = oi; }
            }
            if (col == 0)
                out_idx[tok0 + w * 64 + m * 16 + quad * 4 + r] = mi;
        }
}

// ---------------- kernel 3: gather + transpose-store + fused loss -----------
__global__ __launch_bounds__(256) void k_gather(const float* __restrict__ x,
        const float* __restrict__ cb, const int* __restrict__ idx,
        float* __restrict__ out, float* __restrict__ loss_slot) {
    __shared__ __align__(16) float qs[256 * 36];   // [dim][token(32)+pad]
    __shared__ int sidx[32];
    __shared__ float wpart[4];
    const int t = threadIdx.x;
    const int tb = blockIdx.x * 32;
    const int b = tb >> 11, s0 = tb & 2047;
    if (t < 32) sidx[t] = idx[tb + t];
    __syncthreads();
    {
        int tl = t >> 3, seg = t & 7;
        const float* src = cb + (size_t)sidx[tl] * DIM;
        #pragma unroll
        for (int i = 0; i < 8; ++i) {
            int dim = i * 32 + seg * 4;
            floatx4 v = *(const floatx4*)(src + dim);
            #pragma unroll
            for (int j = 0; j < 4; ++j) qs[(dim + j) * 36 + tl] = v[j];
        }
    }
    __syncthreads();
    float acc = 0.0f;
    {
        int dl = t >> 3, j0 = (t & 7) * 4;
        #pragma unroll
        for (int p = 0; p < 8; ++p) {
            int d = p * 32 + dl;
            size_t g = (size_t)b * DIM * SEQ + (size_t)d * SEQ + s0 + j0;
            floatx4 xv = *(const floatx4*)(x + g);
            floatx4 qv = *(const floatx4*)&qs[d * 36 + j0];
            *(floatx4*)(out + g) = qv;
            floatx4 df = qv - xv;
            acc += df[0]*df[0] + df[1]*df[1] + df[2]*df[2] + df[3]*df[3];
        }
    }
    for (int off = 32; off; off >>= 1) acc += __shfl_xor(acc, off);
    if ((t & 63) == 0) wpart[t >> 6] = acc;
    __syncthreads();
    if (t == 0) {
        float tot = wpart[0] + wpart[1] + wpart[2] + wpart[3];
        atomicAdd(loss_slot, tot * (1.25f / 16777216.0f));
    }
}

extern "C" void kernel_launch(void* const* d_in, const int* in_sizes, int n_in,
                              void* d_out, int out_size, void* d_ws, size_t ws_size,
                              hipStream_t stream) {
    const float* inputs   = (const float*)d_in[0];
    const float* codebook = (const float*)d_in[1];
    float* out = (float*)d_out;
    unsigned short* cb_swz = (unsigned short*)d_ws;                                 // 2 MB
    float* norms = (float*)((char*)d_ws + (size_t)K_CODES * DIM * 2);               // 16 KB
    int* idxbuf  = (int*)((char*)d_ws + (size_t)K_CODES * DIM * 2 + K_CODES * 4);   // 256 KB
    float* loss_slot = out + (out_size - 1);

    hipLaunchKernelGGL(k_prep,   dim3(K_CODES / 32), dim3(256), 0, stream,
                       codebook, cb_swz, norms, loss_slot);
    hipLaunchKernelGGL(k_argmin, dim3(NTOK / 128),   dim3(128), 0, stream,
                       inputs, cb_swz, norms, idxbuf);
    hipLaunchKernelGGL(k_gather, dim3(NTOK / 32),    dim3(256), 0, stream,
                       inputs, codebook, idxbuf, out, loss_slot);
}

// Round 3
// 281.558 us; speedup vs baseline: 1.1488x; 1.1488x over previous
//
#include <hip/hip_runtime.h>

#define K_CODES 4096
#define DIM 256
#define SEQ 2048
#define NTOK 65536

typedef __bf16 bf16x8 __attribute__((ext_vector_type(8)));
typedef float floatx4 __attribute__((ext_vector_type(4)));
typedef unsigned short u16x8 __attribute__((ext_vector_type(8)));

__device__ __forceinline__ unsigned short f2bf(float f) {
    union { float f; unsigned int u; } v; v.f = f;
    unsigned int u = v.u;
    unsigned int r = u + 0x7fffu + ((u >> 16) & 1u);   // RNE
    return (unsigned short)(r >> 16);
}

// ---------------- kernel 1: swizzled bf16 codebook + biased norms -----------
// Swizzle: cb_swz[(((c*16 + ns*8 + ks)*64) + quad*16 + col)*8 + j]
//   = bf16(codebook[c*32 + ns*16 + col][quad*8 + ks*32 + j])
// -> each 1KB fragment block is one wave's lane-contiguous 16B/lane load.
// norms[row] = ||e||^2 + 1.0  (bias keeps distances positive for uint-packed argmin)
__global__ __launch_bounds__(256) void k_prep(const float* __restrict__ cb,
        unsigned short* __restrict__ cb_swz, float* __restrict__ norms,
        float* __restrict__ loss_slot) {
    const int c = blockIdx.x;
    const int t = threadIdx.x;
    const int row_loc = t >> 3;       // 0..31 code within chunk
    const int ks = t & 7;             // k-slice
    const int row = c * 32 + row_loc;
    const float* src = cb + (size_t)row * DIM + ks * 32;
    float vals[32];
    float s = 0.0f;
    #pragma unroll
    for (int i = 0; i < 8; ++i) {
        floatx4 v = *(const floatx4*)(src + i * 4);
        #pragma unroll
        for (int j = 0; j < 4; ++j) { vals[i * 4 + j] = v[j]; s += v[j] * v[j]; }
    }
    const int ns = row_loc >> 4, col = row_loc & 15;
    #pragma unroll
    for (int quad = 0; quad < 4; ++quad) {
        u16x8 p;
        #pragma unroll
        for (int j = 0; j < 8; ++j) p[j] = f2bf(vals[quad * 8 + j]);
        *(u16x8*)(cb_swz + ((size_t)((c * 16 + ns * 8 + ks) * 64 + quad * 16 + col)) * 8) = p;
    }
    s += __shfl_xor(s, 1); s += __shfl_xor(s, 2); s += __shfl_xor(s, 4);
    if (ks == 0) norms[row] = s + 1.0f;
    if (c == 0 && t == 0) *loss_slot = 0.0f;
}

// ---------------- kernel 2: MFMA distance GEMM + packed argmin --------------
// One wave per block, 64 tokens/wave (m=4), codes split in 2 halves of 2048.
// Grid 2048 -> 8 waves/CU = 2/SIMD, all co-resident. NO barriers in main loop;
// B fragments read directly from global (L1/L2-resident swizzled codebook).
__global__ __launch_bounds__(64, 2) void k_argmin(const float* __restrict__ x,
        const unsigned short* __restrict__ cb_swz, const float* __restrict__ norms,
        unsigned int* __restrict__ halfmin) {
    __shared__ __align__(16) unsigned short xs[8448];   // 32 tokens x 264
    const int lane = threadIdx.x;
    const int col = lane & 15, quad = lane >> 4;
    const int bx = blockIdx.x;
    const int h = bx & 1;              // code half: CU-neighbors likely same h -> L1 share
    const int tok0 = (bx >> 1) * 64;
    const int b = tok0 >> 11, s0 = tok0 & 2047;
    const float* xin = x + (size_t)b * DIM * SEQ;

    // ---- one-time X stage (as -2x bf16), two 32-token subgroups
    bf16x8 af[4][8];
    const int dl = lane >> 3, so = (lane & 7) * 4;
    for (int sub = 0; sub < 2; ++sub) {
        const int sbase = s0 + sub * 32;
        for (int i = 0; i < 32; ++i) {
            int d = i * 8 + dl;
            floatx4 v = *(const floatx4*)(xin + (size_t)d * SEQ + sbase + so);
            #pragma unroll
            for (int j = 0; j < 4; ++j) xs[(so + j) * 264 + d] = f2bf(-2.0f * v[j]);
        }
        __builtin_amdgcn_s_waitcnt(0);   // single wave: just drain LDS writes
        #pragma unroll
        for (int mm = 0; mm < 2; ++mm)
            #pragma unroll
            for (int ks = 0; ks < 8; ++ks)
                af[sub * 2 + mm][ks] =
                    *(const bf16x8*)&xs[(mm * 16 + col) * 264 + quad * 8 + ks * 32];
        __builtin_amdgcn_s_waitcnt(0);
    }

    unsigned int minkey[4][4];
    #pragma unroll
    for (int m = 0; m < 4; ++m)
        #pragma unroll
        for (int r = 0; r < 4; ++r) minkey[m][r] = 0xFFFFFFFFu;

    for (int c = 0; c < 64; ++c) {
        const int gc = h * 64 + c;
        #pragma unroll
        for (int ns = 0; ns < 2; ++ns) {
            const float nv = norms[gc * 32 + ns * 16 + col];
            bf16x8 bfrag[8];
            #pragma unroll
            for (int ks = 0; ks < 8; ++ks)   // 1KB coalesced, L1/L2-resident
                bfrag[ks] = *(const bf16x8*)(cb_swz +
                    ((size_t)((gc * 16 + ns * 8 + ks) * 64) + lane) * 8);
            floatx4 acc[4];
            #pragma unroll
            for (int m = 0; m < 4; ++m) acc[m] = (floatx4){nv, nv, nv, nv};
            #pragma unroll
            for (int ks = 0; ks < 8; ++ks)
                #pragma unroll
                for (int m = 0; m < 4; ++m)
                    acc[m] = __builtin_amdgcn_mfma_f32_16x16x32_bf16(
                                 af[m][ks], bfrag[ks], acc[m], 0, 0, 0);
            const unsigned int code = gc * 32 + ns * 16 + col;
            #pragma unroll
            for (int m = 0; m < 4; ++m)
                #pragma unroll
                for (int r = 0; r < 4; ++r) {
                    unsigned int key = (__float_as_uint(acc[m][r]) & 0xFFFFF000u) | code;
                    minkey[m][r] = key < minkey[m][r] ? key : minkey[m][r];
                }
        }
    }

    // ---- min over the 16 column-lanes, write packed (dist|code) per token
    #pragma unroll
    for (int m = 0; m < 4; ++m)
        #pragma unroll
        for (int r = 0; r < 4; ++r) {
            unsigned int k = minkey[m][r];
            #pragma unroll
            for (int off = 8; off >= 1; off >>= 1) {
                unsigned int o = __shfl_xor(k, off);
                k = o < k ? o : k;
            }
            if (col == 0)
                halfmin[h * NTOK + tok0 + m * 16 + quad * 4 + r] = k;
        }
}

// ---------------- kernel 3: merge halves + gather + transpose + loss --------
// 512 threads, 64 tokens/block -> 256B coalesced out-stores. Swizzled LDS.
__global__ __launch_bounds__(512) void k_gather(const float* __restrict__ x,
        const float* __restrict__ cb, const unsigned int* __restrict__ halfmin,
        float* __restrict__ out, float* __restrict__ loss_slot) {
    __shared__ __align__(16) float qs[256 * 64];   // 64 KB, swizzled columns
    __shared__ int sidx[64];
    __shared__ float wpart[8];
    const int t = threadIdx.x;
    const int tb = blockIdx.x * 64;
    const int b = tb >> 11, s0 = tb & 2047;
    if (t < 64) {
        unsigned int p0 = halfmin[tb + t], p1 = halfmin[NTOK + tb + t];
        sidx[t] = (int)((p0 < p1 ? p0 : p1) & 0xFFFu);
    }
    __syncthreads();
    {   // gather cb rows -> qs[dim][tok], column swizzled by (dim>>5)*8
        const int tl = t >> 3, seg = t & 7;
        const float* src = cb + (size_t)sidx[tl] * DIM + seg * 32;
        const int pos = (tl + seg * 8) & 63;
        #pragma unroll
        for (int i = 0; i < 8; ++i) {
            floatx4 v = *(const floatx4*)(src + i * 4);
            #pragma unroll
            for (int j = 0; j < 4; ++j) qs[(seg * 32 + i * 4 + j) * 64 + pos] = v[j];
        }
    }
    __syncthreads();
    float acc = 0.0f;
    {
        const int d0 = t >> 4, j0 = (t & 15) * 4;
        #pragma unroll
        for (int dd = 0; dd < 8; ++dd) {
            int d = dd * 32 + d0;
            size_t g = (size_t)b * DIM * SEQ + (size_t)d * SEQ + s0 + j0;
            floatx4 xv = *(const floatx4*)(x + g);
            floatx4 qv = *(const floatx4*)&qs[d * 64 + ((j0 + (d >> 5) * 8) & 63)];
            *(floatx4*)(out + g) = qv;
            floatx4 df = qv - xv;
            acc += df[0]*df[0] + df[1]*df[1] + df[2]*df[2] + df[3]*df[3];
        }
    }
    for (int off = 32; off; off >>= 1) acc += __shfl_xor(acc, off);
    if ((t & 63) == 0) wpart[t >> 6] = acc;
    __syncthreads();
    if (t == 0) {
        float tot = 0.0f;
        #pragma unroll
        for (int i = 0; i < 8; ++i) tot += wpart[i];
        atomicAdd(loss_slot, tot * (1.25f / 16777216.0f));
    }
}

extern "C" void kernel_launch(void* const* d_in, const int* in_sizes, int n_in,
                              void* d_out, int out_size, void* d_ws, size_t ws_size,
                              hipStream_t stream) {
    const float* inputs   = (const float*)d_in[0];
    const float* codebook = (const float*)d_in[1];
    float* out = (float*)d_out;
    unsigned short* cb_swz = (unsigned short*)d_ws;                                  // 2 MB
    float* norms = (float*)((char*)d_ws + (size_t)K_CODES * DIM * 2);                // 16 KB
    unsigned int* halfmin = (unsigned int*)((char*)d_ws + (size_t)K_CODES * DIM * 2
                                            + K_CODES * 4);                          // 512 KB
    float* loss_slot = out + (out_size - 1);

    hipLaunchKernelGGL(k_prep,   dim3(K_CODES / 32), dim3(256), 0, stream,
                       codebook, cb_swz, norms, loss_slot);
    hipLaunchKernelGGL(k_argmin, dim3(NTOK / 64 * 2), dim3(64), 0, stream,
                       inputs, cb_swz, norms, halfmin);
    hipLaunchKernelGGL(k_gather, dim3(NTOK / 64), dim3(512), 0, stream,
                       inputs, codebook, halfmin, out, loss_slot);
}